// Round 14
// baseline (242.508 us; speedup 1.0000x reference)
//
#include <hip/hip_runtime.h>
#include <hip/hip_bf16.h>

#define N_NODES 10000
#define N_EDGES 320000
#define N_REL   460
#define N_BASES 30
#define DIM     200
#define KZ      6016   // 30*200=6000 padded to multiple of 32
#define KT      6240   // KZ + 224 (self-term columns appended)
#define NSTEPS  195    // KT/32
#define NTILES  157    // ceil(10000/64)
#define NFRAG   16     // col fragments of 16 (13 real, 3 zero-padded)
#define KSPLIT  8
#define PROWS   10048  // 157*64
#define TKELEM  2048   // ASW elements per (tile,kstep): 4 sub x 16 rows x 32 cols

#define PREP_C  (N_REL * 16)             // 7360
#define PREP_X8 (N_NODES * 28)           // 280000 (28 pair-tasks/node)
#define HIST_BLOCKS ((N_EDGES + PREP_C + 255) / 256)   // 1280
#define S2_TOTAL (N_EDGES + PREP_X8)

using short8  = __attribute__((ext_vector_type(8))) short;
using s4v     = __attribute__((ext_vector_type(4))) short;
using floatx4 = __attribute__((ext_vector_type(4))) float;

__device__ __forceinline__ unsigned short f2bf(float f) {
    union { float f; unsigned u; } v; v.f = f;
    unsigned u = v.u;
    return (unsigned short)((u + 0x7fffu + ((u >> 16) & 1u)) >> 16);
}

__device__ __forceinline__ float bf2f(unsigned short s) {
    union { unsigned u; float f; } v;
    v.u = ((unsigned)s) << 16;
    return v.f;
}

__device__ __forceinline__ short8 pack8(const unsigned short* u) {
    union { unsigned short s[8]; short8 v; } p;
#pragma unroll
    for (int i = 0; i < 8; ++i) p.s[i] = u[i];
    return p.v;
}

// ASW v3: 64-row tiles. Element (node n, col c):
//   t=n>>6, sub=(n>>4)&3, rl=n&15; kk=c>>5, w=c&31
//   idx = (t*195+kk)*2048 + sub*512 + rl*32 + w
__device__ __forceinline__ size_t asw_idx(int n, int c) {
    int t = n >> 6, sub = (n >> 4) & 3, rl = n & 15;
    int kk = c >> 5, w = c & 31;
    return (size_t)(t * NSTEPS + kk) * TKELEM + sub * 512 + rl * 32 + w;
}

// ---------------- sort phase 1: hist + Cpair + BSW transpose (block-specialized) ----
// R27: blocks < HIST_BLOCKS: edge histogram + Cpair (unchanged). Blocks >=
// HIST_BLOCKS each own one kstep kk of the BSW transpose: load 32 k-rows x
// 200 cols of weight/sw CONTIGUOUSLY (float4 row reads — the old version did
// 12.8M scalar stride-800B column reads, the largest hidden cost), bf16 them
// into a padded LDS tile [32][209], emit 16 frag blocks as coalesced short8.
// Bit-identical BSW bytes: same f2bf, zeros for k in [6000,6016), jj>=200,
// rB>=200.

__global__ __launch_bounds__(256) void sort1_kernel(const int* __restrict__ tgt, int* __restrict__ deg,
                             const float* __restrict__ weight, const float* __restrict__ sw,
                             const float* __restrict__ coeff,
                             unsigned short* __restrict__ BSW, unsigned int* __restrict__ Cpair) {
    __shared__ unsigned short T[32][209];
    if (blockIdx.x >= HIST_BLOCKS) {
        int kk = blockIdx.x - HIST_BLOCKS;        // 0..194
        int tid = threadIdx.x;
        // load phase: 32 rows x 50 float4 (contiguous within each k-row)
        for (int v = tid; v < 32 * 50; v += 256) {
            int r = v / 50, q4 = v - r * 50;
            int kg = kk * 32 + r;
            floatx4 w = (floatx4){0.f, 0.f, 0.f, 0.f};
            if (kg < N_BASES * DIM) {
                w = *(const floatx4*)(weight + (size_t)kg * DIM + q4 * 4);
            } else if (kg >= KZ && kg < KZ + DIM) {
                w = *(const floatx4*)(sw + (size_t)(kg - KZ) * DIM + q4 * 4);
            }
            T[r][q4 * 4 + 0] = f2bf(w[0]);
            T[r][q4 * 4 + 1] = f2bf(w[1]);
            T[r][q4 * 4 + 2] = f2bf(w[2]);
            T[r][q4 * 4 + 3] = f2bf(w[3]);
        }
        __syncthreads();
        // write phase: 16 frags x 64 lanes, coalesced short8 stores
        for (int v = tid; v < 16 * 64; v += 256) {
            int f = v >> 6, l = v & 63;
            int rB = f * 16 + (l & 15);
            int kr = (l >> 4) * 8;
            unsigned short bs[8];
#pragma unroll
            for (int j = 0; j < 8; ++j)
                bs[j] = (rB < DIM) ? T[kr + j][rB] : (unsigned short)0;
            *(short8*)(BSW + ((size_t)f * NSTEPS + kk) * 512 + l * 8) = pack8(bs);
        }
        return;
    }
    int idx = blockIdx.x * blockDim.x + threadIdx.x;
    if (idx < N_EDGES) {
        atomicAdd(&deg[tgt[idx]], 1);
        return;
    }
    idx -= N_EDGES;
    if (idx < PREP_C) {
        int t = idx >> 4, m = idx & 15;
        unsigned lo = f2bf(coeff[t * N_BASES + m]);
        unsigned hi = (m + 16 < N_BASES) ? f2bf(coeff[t * N_BASES + m + 16]) : 0u;
        Cpair[idx] = lo | (hi << 16);
    }
}

__global__ __launch_bounds__(1024) void scan_kernel(const int* deg, int* starts,
                                                    int* cursor, float* dinv) {
    __shared__ int part[1024];
    int tid = threadIdx.x;
    const int PER = (N_NODES + 1023) / 1024;  // 10
    int base = tid * PER;
    int s = 0;
    for (int i = 0; i < PER; ++i) { int idx = base + i; if (idx < N_NODES) s += deg[idx]; }
    part[tid] = s; __syncthreads();
    for (int off = 1; off < 1024; off <<= 1) {
        int v = (tid >= off) ? part[tid - off] : 0;
        __syncthreads();
        part[tid] += v;
        __syncthreads();
    }
    int run = (tid > 0) ? part[tid - 1] : 0;
    for (int i = 0; i < PER; ++i) {
        int idx = base + i;
        if (idx < N_NODES) {
            int d = deg[idx];
            starts[idx] = run; cursor[idx] = run;
            dinv[idx] = 1.0f / (float)(d > 0 ? d : 1);
            run += d;
        }
    }
    if (tid == 1023) starts[N_NODES] = part[1023];
}

// ---------------- sort phase 2: scatter + deg-dependent prep (XbfP, ASW self) ----------------
// R23 layout (validated R10): XbfP slot (p,c) holds (x[n][p*32+c], x[n][p*32+16+c])
// as (lo,hi) bf16. Cols >= 200 explicit zeros (land only in discarded out cols).

__global__ void sort2_kernel(const int* __restrict__ src, const int* __restrict__ tgt,
                             const int* __restrict__ etype, int* __restrict__ cursor,
                             int2* __restrict__ sedge,
                             const float* __restrict__ x, const int* __restrict__ deg,
                             unsigned short* __restrict__ XbfP, unsigned short* __restrict__ ASW) {
    int idx = blockIdx.x * blockDim.x + threadIdx.x;
    if (idx < N_EDGES) {
        int t = tgt[idx];
        int pos = atomicAdd(&cursor[t], 1);
        sedge[pos] = make_int2(src[idx], etype[idx]);
        return;
    }
    idx -= N_EDGES;
    if (idx < PREP_X8) {
        int n = idx / 28, t = idx - n * 28;
        int p = t >> 2, c4 = (t & 3) << 2;
        int cl = p * 32 + c4;            // lo col base (cl..cl+3)
        int ch = cl + 16;                // hi col base (ch..ch+3)
        int d = deg[n]; if (d < 1) d = 1;
        float df = (float)d;
        floatx4 vlo = (floatx4){0.f, 0.f, 0.f, 0.f};
        floatx4 vhi = (floatx4){0.f, 0.f, 0.f, 0.f};
        if (cl < DIM) vlo = *(const floatx4*)(x + (size_t)n * DIM + cl);
        if (ch < DIM) vhi = *(const floatx4*)(x + (size_t)n * DIM + ch);
        unsigned short xp[8], asl[4], ash[4];
#pragma unroll
        for (int i = 0; i < 4; ++i) {
            xp[2 * i]     = f2bf(vlo[i]);
            xp[2 * i + 1] = f2bf(vhi[i]);
            asl[i] = f2bf(df * vlo[i]);
            ash[i] = f2bf(df * vhi[i]);
        }
        *(short8*)(XbfP + (size_t)n * 224 + p * 32 + c4 * 2) = pack8(xp);
        union { unsigned short s[4]; s4v v; } ul, uh;
#pragma unroll
        for (int i = 0; i < 4; ++i) { ul.s[i] = asl[i]; uh.s[i] = ash[i]; }
        *(s4v*)(ASW + asw_idx(n, KZ + cl)) = ul.v;
        *(s4v*)(ASW + asw_idx(n, KZ + ch)) = uh.v;
    }
}

// ---------------- per-target-node aggregation via MFMA ----------------
// R26 (validated R13): node split across TWO waves by coefficient half.
// Per accumulator the MFMA set and order are identical => bit-identical.

__global__ __launch_bounds__(256) void agg_kernel(const unsigned int* __restrict__ XbfP,
                                                  const unsigned int* __restrict__ Cpair,
                                                  const int* __restrict__ starts,
                                                  const int2* __restrict__ sedge,
                                                  unsigned short* __restrict__ ASW) {
    __shared__ __align__(16) unsigned short zbuf[4][3232];  // 25856 B/block
    int lane = threadIdx.x & 63;
    int wave = threadIdx.x >> 6;
    int n = blockIdx.x * 2 + (wave >> 1);     // 5000*2 == 10000 exactly
    int h = wave & 1;                         // 0: bases 0-15, 1: bases 16-29
    int ln = lane & 15, q = lane >> 4;

    floatx4 acc[13];
#pragma unroll
    for (int f = 0; f < 13; ++f) acc[f] = (floatx4){0.f, 0.f, 0.f, 0.f};

    int e0 = starts[n], e1 = starts[n + 1];
    for (int kb = e0; kb < e1; kb += 32) {
        int eb = kb + 8 * q;
        unsigned short av[8];
        int srcs[8];
#pragma unroll
        for (int j = 0; j < 8; ++j) {
            int e = eb + j;
            int ec = (e < e1) ? e : (e1 - 1);
            int2 sd = sedge[ec];
            unsigned cp = (e < e1) ? Cpair[sd.y * 16 + ln] : 0u;
            av[j] = h ? (unsigned short)(cp >> 16) : (unsigned short)(cp & 0xffffu);
            srcs[j] = sd.x;
        }
        short8 A = pack8(av);

        unsigned pv[2][8];
#pragma unroll
        for (int j = 0; j < 8; ++j)
            pv[0][j] = XbfP[(size_t)srcs[j] * 112 + ln];
#pragma unroll
        for (int p = 0; p < 7; ++p) {
            int cur = p & 1, nxt = cur ^ 1;
            if (p < 6) {
#pragma unroll
                for (int j = 0; j < 8; ++j)
                    pv[nxt][j] = XbfP[(size_t)srcs[j] * 112 + (p + 1) * 16 + ln];
            }
            unsigned short lo[8], hi[8];
#pragma unroll
            for (int j = 0; j < 8; ++j) {
                lo[j] = (unsigned short)(pv[cur][j] & 0xffffu);
                hi[j] = (unsigned short)(pv[cur][j] >> 16);
            }
            short8 Blo = pack8(lo), Bhi = pack8(hi);
            int f0 = 2 * p;
            acc[f0] = __builtin_amdgcn_mfma_f32_16x16x32_bf16(A, Blo, acc[f0], 0, 0, 0);
            if (2 * p + 1 < 13)
                acc[2 * p + 1] = __builtin_amdgcn_mfma_f32_16x16x32_bf16(A, Bhi, acc[2 * p + 1], 0, 0, 0);
        }
    }

    unsigned short* zb = zbuf[wave];
    int t = n >> 6, sub = (n >> 4) & 3, rl = n & 15;
    const uint4* zb4 = (const uint4*)zb;
    uint4* dst = (uint4*)ASW;
    size_t base_u4 = (size_t)t * NSTEPS * 256 + sub * 64 + rl * 4;

    if (h == 0) {
        // bases 0..15 -> cols [0,3200), ksteps 0..99
#pragma unroll
        for (int f = 0; f < 13; ++f) {
            int d = f * 16 + ln;
            if (d < DIM) {
#pragma unroll
                for (int i = 0; i < 4; ++i)
                    zb[(q * 4 + i) * DIM + d] = f2bf(acc[f][i]);
            }
        }
        for (int v = lane; v < 400; v += 64) {
            int kk = v >> 2, w8 = v & 3;
            dst[base_u4 + (size_t)kk * 256 + w8] = zb4[v];
        }
    } else {
        // bases 16..29 -> cols [3200,6000) + pad, ksteps 100..187
        if (lane < 16) zb[2800 + lane] = 0;
#pragma unroll
        for (int f = 0; f < 13; ++f) {
            int d = f * 16 + ln;
            if (d < DIM) {
#pragma unroll
                for (int i = 0; i < 4; ++i) {
                    int b1 = 16 + q * 4 + i;
                    if (b1 < N_BASES) zb[(q * 4 + i) * DIM + d] = f2bf(acc[f][i]);
                }
            }
        }
        for (int v = lane; v < 352; v += 64) {
            int kk = 100 + (v >> 2), w8 = v & 3;
            dst[base_u4 + (size_t)kk * 256 + w8] = zb4[v];
        }
    }
}

// ---------------- GEMM: part[chunk] = A_ext @ B_ext^T over K-chunk ----------------
// R25 (validated R12). A staged via global_load_lds, 4 LDS slots (16 KB),
// KSPLIT=8, bf16 partials; depth-3 pipeline, head immediates 0/4/8, steady 8.

#define GITER(VLIT, BU, BL, KK)                                                        \
  {                                                                                    \
    asm volatile("s_waitcnt vmcnt(" #VLIT ")" ::: "memory");                           \
    __builtin_amdgcn_sched_barrier(0);                                                 \
    asm volatile("s_barrier" ::: "memory");                                            \
    const int kk_ = (KK);                                                              \
    const int kld_ = (kk_ + 1 < ke) ? kk_ + 1 : ke - 1;                                \
    BL[0] = *(const short8*)(pb + ((size_t)(0 * 4 * NSTEPS) + kld_) * 512);            \
    BL[1] = *(const short8*)(pb + ((size_t)(1 * 4 * NSTEPS) + kld_) * 512);            \
    BL[2] = *(const short8*)(pb + ((size_t)(2 * 4 * NSTEPS) + kld_) * 512);            \
    BL[3] = *(const short8*)(pb + ((size_t)(3 * 4 * NSTEPS) + kld_) * 512);            \
    const int kst_ = (kk_ + 3 < ke) ? kk_ + 3 : ke - 1;                                \
    __builtin_amdgcn_global_load_lds(                                                  \
        (const unsigned int*)(aswt + (size_t)kst_ * TKELEM + goff),                    \
        (unsigned int*)(ldsw + ((kk_ + 3) & 3) * 2048), 16, 0, 0);                     \
    const unsigned short* sp_ = alds + (kk_ & 3) * 2048 + pread8;                      \
    short8 av0 = *(const short8*)(sp_);                                                \
    short8 av1 = *(const short8*)(sp_ + 512);                                          \
    short8 av2 = *(const short8*)(sp_ + 1024);                                         \
    short8 av3 = *(const short8*)(sp_ + 1536);                                         \
    _Pragma("unroll")                                                                  \
    for (int i_ = 0; i_ < 4; ++i_) {                                                   \
      acc[i_][0] = __builtin_amdgcn_mfma_f32_16x16x32_bf16(av0, BU[i_], acc[i_][0], 0, 0, 0); \
      acc[i_][1] = __builtin_amdgcn_mfma_f32_16x16x32_bf16(av1, BU[i_], acc[i_][1], 0, 0, 0); \
      acc[i_][2] = __builtin_amdgcn_mfma_f32_16x16x32_bf16(av2, BU[i_], acc[i_][2], 0, 0, 0); \
      acc[i_][3] = __builtin_amdgcn_mfma_f32_16x16x32_bf16(av3, BU[i_], acc[i_][3], 0, 0, 0); \
    }                                                                                  \
  }

__global__ __launch_bounds__(256, 4) void gemm_kernel(const unsigned short* __restrict__ ASW,
                                                      const unsigned short* __restrict__ BSW,
                                                      unsigned short* __restrict__ part) {
    __shared__ __align__(16) unsigned short alds[4 * 2048];   // 16 KB: 4 slots x 4 KB
    int tid = threadIdx.x;
    int lane = tid & 63, wave = tid >> 6;
    int tile = blockIdx.x, chunk = blockIdx.y;
    int ks = (chunk * NSTEPS) / KSPLIT;
    int ke = ((chunk + 1) * NSTEPS) / KSPLIT;
    int ln = lane & 15, q = lane >> 4;

    const unsigned short* aswt = ASW + (size_t)tile * NSTEPS * TKELEM;
    const unsigned short* pb = BSW + (size_t)(wave * NSTEPS) * 512 + lane * 8;

    // global source chunk permutation (involution pair with pread below):
    int gsw = (tid & 0xE0) | ((tid & 7) << 2) | ((tid >> 3) & 3);
    int goff = gsw * 8;                        // ushort elements
    // read chunk index: 8-lane groups hit 8 distinct 4-bank groups => conflict-free
    int pread8 = ((((ln >> 3) & 1) << 5) | (q << 3) | (ln & 7)) * 8;
    unsigned short* ldsw = alds + wave * 512;  // this wave's linear 1 KB dest

    floatx4 acc[4][4];   // [frag][sub]
#pragma unroll
    for (int i = 0; i < 4; ++i)
#pragma unroll
        for (int s = 0; s < 4; ++s) acc[i][s] = (floatx4){0.f, 0.f, 0.f, 0.f};

    short8 bA[4], bB[4];

    // prologue: b(ks) + stages ks..ks+2 (chunk length 24 or 25 >= 4)
#pragma unroll
    for (int i = 0; i < 4; ++i)
        bA[i] = *(const short8*)(pb + ((size_t)(i * 4 * NSTEPS) + ks) * 512);
#pragma unroll
    for (int d = 0; d < 3; ++d)
        __builtin_amdgcn_global_load_lds(
            (const unsigned int*)(aswt + (size_t)(ks + d) * TKELEM + goff),
            (unsigned int*)(ldsw + ((ks + d) & 3) * 2048), 16, 0, 0);

    // peeled head: DMA(ks+t) has {2,6,10} VMEM ops after it at top of iter t;
    // conservative immediates 0/4/8 (steady 8)
    GITER(0, bA, bB, ks + 0);
    GITER(4, bB, bA, ks + 1);
    GITER(8, bA, bB, ks + 2);

    int kk = ks + 3;
    for (; kk + 1 < ke; kk += 2) {
        GITER(8, bB, bA, kk);
        GITER(8, bA, bB, kk + 1);
    }
    if (kk < ke) { GITER(8, bB, bA, kk); }

    int row0 = tile * 64;
    unsigned short* pbase = part + ((size_t)chunk * PROWS + row0) * 208;
#pragma unroll
    for (int i = 0; i < 4; ++i) {
        int fg = wave + 4 * i;
        if (fg < 13) {
            int c = fg * 16 + ln;
#pragma unroll
            for (int s = 0; s < 4; ++s)
#pragma unroll
                for (int ii = 0; ii < 4; ++ii)
                    pbase[(s * 16 + q * 4 + ii) * 208 + c] = f2bf(acc[i][s][ii]);
        }
    }
}

// ---------------- reduce: out = dinv * sum(bf16 partials) + bias ----------------

__global__ __launch_bounds__(256) void reduce_kernel(const unsigned short* __restrict__ part,
                                                     const float* __restrict__ dinv,
                                                     const float* __restrict__ bias,
                                                     float* __restrict__ out) {
    int idx = blockIdx.x * blockDim.x + threadIdx.x;
    if (idx >= N_NODES * 50) return;
    int r = idx / 50, cq = idx - r * 50;
    float s0 = 0.f, s1 = 0.f, s2 = 0.f, s3 = 0.f;
#pragma unroll
    for (int c = 0; c < KSPLIT; ++c) {
        union { unsigned short s[4]; s4v v; } u;
        u.v = *(const s4v*)(part + ((size_t)c * PROWS + r) * 208 + cq * 4);
        s0 += bf2f(u.s[0]); s1 += bf2f(u.s[1]);
        s2 += bf2f(u.s[2]); s3 += bf2f(u.s[3]);
    }
    float dv = dinv[r];
    float4 b = *(const float4*)(bias + cq * 4);
    float4 o;
    o.x = s0 * dv + b.x; o.y = s1 * dv + b.y;
    o.z = s2 * dv + b.z; o.w = s3 * dv + b.w;
    *(float4*)(out + (size_t)r * DIM + cq * 4) = o;
}

// ---------------- launch ----------------

extern "C" void kernel_launch(void* const* d_in, const int* in_sizes, int n_in,
                              void* d_out, int out_size, void* d_ws, size_t ws_size,
                              hipStream_t stream) {
    const float* x      = (const float*)d_in[0];
    const float* weight = (const float*)d_in[1];
    const float* coeff  = (const float*)d_in[2];
    const float* selfw  = (const float*)d_in[3];
    const float* bias   = (const float*)d_in[4];
    const int*   eidx   = (const int*)d_in[5];
    const int*   etype  = (const int*)d_in[6];
    const int* src = eidx;
    const int* tgt = eidx + N_EDGES;
    float* out = (float*)d_out;

    char* ws = (char*)d_ws;
    size_t off = 0;
    auto carve = [&](size_t bytes) {
        char* p = ws + off;
        off += (bytes + 255) & ~(size_t)255;
        return p;
    };
    unsigned short* ASW  = (unsigned short*)carve((size_t)NTILES * NSTEPS * TKELEM * 2);  // 125.4 MB
    unsigned short* BSW  = (unsigned short*)carve((size_t)NFRAG * NSTEPS * 512 * 2);
    unsigned short* part = (unsigned short*)carve((size_t)KSPLIT * PROWS * 208 * 2);      // 33.4 MB bf16
    unsigned short* XbfP = (unsigned short*)carve((size_t)(N_NODES * 224 + 64) * 2);      // 4.5 MB paired
    unsigned int*  Cpair = (unsigned int*)carve((size_t)N_REL * 16 * 4);
    int*   deg    = (int*)carve((size_t)N_NODES * 4);
    int*   starts = (int*)carve((size_t)(N_NODES + 1) * 4);
    int*   cursor = (int*)carve((size_t)N_NODES * 4);
    float* dinv   = (float*)carve((size_t)N_NODES * 4);
    int2*  sedge  = (int2*)carve((size_t)N_EDGES * 8);

    hipMemsetAsync(deg, 0, (size_t)N_NODES * 4, stream);

    sort1_kernel<<<HIST_BLOCKS + NSTEPS, 256, 0, stream>>>(
        tgt, deg, weight, selfw, coeff, BSW, Cpair);

    scan_kernel<<<1, 1024, 0, stream>>>(deg, starts, cursor, dinv);

    sort2_kernel<<<(S2_TOTAL + 255) / 256, 256, 0, stream>>>(
        src, tgt, etype, cursor, sedge, x, deg, XbfP, ASW);

    agg_kernel<<<N_NODES / 2, 256, 0, stream>>>(
        (const unsigned int*)XbfP, Cpair, starts, sedge, ASW);

    dim3 ggrid(NTILES, KSPLIT);
    gemm_kernel<<<ggrid, 256, 0, stream>>>(ASW, BSW, part);

    reduce_kernel<<<(N_NODES * 50 + 255) / 256, 256, 0, stream>>>(part, dinv, bias, out);
}